// Round 5
// baseline (970.174 us; speedup 1.0000x reference)
//
#include <hip/hip_runtime.h>
#include <math.h>

#define N_NODES 100000
#define N_EDGES 3200000
#define F_IN    512
#define HID     16
#define NCLS    7
#define ALPHA   0.1f
#define K_HOPS  10

// bucketing: 128 nodes per bucket
#define SHIFT   7
#define BWIDTH  128
#define NBUCK   ((N_NODES + BWIDTH - 1) / BWIDTH)   // 782
#define CHUNK   8192
#define EPT     (CHUNK / 256)                        // 32 edges per thread
#define A3_BLOCKS ((N_EDGES + CHUNK - 1) / CHUNK)   // 391

// ---- workspace layout (4-byte element offsets); ws_size ~819 MB, no aliasing needed ----
#define OFF_BCNT    0u         // int[782]
#define OFF_BSTART  1024u      // int[783]
#define OFF_BCUR    2048u      // int[782]
#define OFF_DINV    3072u      // float[100000]
#define OFF_BINNED  103424u    // uint[3200000]
#define OFF_H0      3303424u   // float[100000*16]
#define OFF_H1      4903424u   // float[100000*16]
#define OFF_Z       6503424u   // float[100000*8]
// total = 7303424 elems = 29.2 MB

// ---------------- A1: global bucket histogram ----------------
__global__ void k_bhist(const int* __restrict__ dst, int* __restrict__ bcnt) {
    __shared__ int h[NBUCK];
    int tid = threadIdx.x;
    for (int i = tid; i < NBUCK; i += 256) h[i] = 0;
    __syncthreads();
    for (int e = blockIdx.x * 256 + tid; e < N_EDGES; e += gridDim.x * 256)
        atomicAdd(&h[dst[e] >> SHIFT], 1);
    __syncthreads();
    for (int i = tid; i < NBUCK; i += 256) {
        int v = h[i];
        if (v) atomicAdd(&bcnt[i], v);
    }
}

// ---------------- A2: scan bucket counts ----------------
__global__ void k_bscan(const int* __restrict__ bcnt, int* __restrict__ bstart,
                        int* __restrict__ bcur) {
    __shared__ int s[1024];
    int tid = threadIdx.x;
    int v = (tid < NBUCK) ? bcnt[tid] : 0;
    s[tid] = v;
    __syncthreads();
    for (int off = 1; off < 1024; off <<= 1) {
        int t = (tid >= off) ? s[tid - off] : 0;
        __syncthreads();
        s[tid] += t;
        __syncthreads();
    }
    if (tid < NBUCK) {
        int ex = s[tid] - v;     // exclusive
        bstart[tid] = ex;
        bcur[tid] = ex;
    }
    if (tid == 0) bstart[NBUCK] = N_EDGES;
}

// ---------------- A3: binned scatter of packed edges ----------------
// binned[pos] = (dst&127)<<17 | src   (src < 2^17); dst cached in regs across passes
__global__ void k_bin(const int* __restrict__ src, const int* __restrict__ dst,
                      int* __restrict__ bcur, unsigned int* __restrict__ binned) {
    __shared__ int ha[NBUCK];
    __shared__ int gbase[NBUCK];
    __shared__ int lcur[NBUCK];
    int tid = threadIdx.x;
    int e0 = blockIdx.x * CHUNK;
    int e1 = e0 + CHUNK;
    if (e1 > N_EDGES) e1 = N_EDGES;
    for (int i = tid; i < NBUCK; i += 256) ha[i] = 0;
    __syncthreads();
    int dloc[EPT];
#pragma unroll
    for (int i = 0; i < EPT; i++) {
        int e = e0 + tid + i * 256;
        dloc[i] = (e < e1) ? dst[e] : -1;
        if (dloc[i] >= 0) atomicAdd(&ha[dloc[i] >> SHIFT], 1);
    }
    __syncthreads();
    for (int s = tid; s < NBUCK; s += 256) {
        int c = ha[s];
        lcur[s] = 0;
        gbase[s] = c ? atomicAdd(&bcur[s], c) : 0;
    }
    __syncthreads();
#pragma unroll
    for (int i = 0; i < EPT; i++) {
        int d = dloc[i];
        if (d >= 0) {
            int e = e0 + tid + i * 256;
            int bk = d >> SHIFT;
            int idx = atomicAdd(&lcur[bk], 1);
            binned[gbase[bk] + idx] =
                ((unsigned int)(d & (BWIDTH - 1)) << 17) | (unsigned int)src[e];
        }
    }
}

// ---------------- deg/dinv from binned windows (one block per bucket) ----------------
__global__ void k_deg(const unsigned int* __restrict__ binned, const int* __restrict__ bstart,
                      float* __restrict__ dinv) {
    __shared__ int cnt[BWIDTH];
    int tid = threadIdx.x;
    int b = blockIdx.x;
    int base = b << SHIFT;
    if (tid < BWIDTH) cnt[tid] = 0;
    __syncthreads();
    int e0 = bstart[b], e1 = bstart[b + 1];
    for (int e = e0 + tid; e < e1; e += 256)
        atomicAdd(&cnt[binned[e] >> 17], 1);
    __syncthreads();
    if (tid < BWIDTH) {
        int node = base + tid;
        if (node < N_NODES) dinv[node] = rsqrtf((float)(cnt[tid] + 1));
    }
}

// ---------------- h0s = dinv * (x @ W1): coalesced LDS-tiled GEMM ----------------
#define XW_ROWS 64
#define XW_KT   32
#define XW_S    65
#define XW_NT   (F_IN / XW_KT)   // 16 tiles
__global__ void k_xw1(const float* __restrict__ x, const float* __restrict__ W,
                      const float* __restrict__ dinv, float* __restrict__ h0s) {
    __shared__ float xT[2][XW_KT * XW_S];
    int tid = threadIdx.x;
    int rowBase = blockIdx.x * XW_ROWS;

    int rf0 = tid >> 3, kq = tid & 7;
    int rf1 = rf0 + 32;
    bool v0 = (rowBase + rf0) < N_NODES;
    bool v1 = (rowBase + rf1) < N_NODES;
    const float* xrow0 = x + (size_t)(rowBase + rf0) * F_IN;
    const float* xrow1 = x + (size_t)(rowBase + rf1) * F_IN;

    int r  = tid & 63;
    int cg = __builtin_amdgcn_readfirstlane(tid >> 6);   // wave-uniform -> s_load W
    const float4* W4 = (const float4*)W;

    float4 zero4 = make_float4(0.f, 0.f, 0.f, 0.f);
    float4 acc = zero4;
    float4 ld0 = v0 ? ((const float4*)xrow0)[kq] : zero4;
    float4 ld1 = v1 ? ((const float4*)xrow1)[kq] : zero4;

    for (int kt = 0; kt < XW_NT; kt++) {
        int buf = kt & 1;
        float* xb = xT[buf];
        int kb = kq * 4;
        xb[(kb + 0) * XW_S + rf0] = ld0.x;
        xb[(kb + 1) * XW_S + rf0] = ld0.y;
        xb[(kb + 2) * XW_S + rf0] = ld0.z;
        xb[(kb + 3) * XW_S + rf0] = ld0.w;
        xb[(kb + 0) * XW_S + rf1] = ld1.x;
        xb[(kb + 1) * XW_S + rf1] = ld1.y;
        xb[(kb + 2) * XW_S + rf1] = ld1.z;
        xb[(kb + 3) * XW_S + rf1] = ld1.w;
        if (kt + 1 < XW_NT) {
            const float4* p0 = (const float4*)(xrow0 + (kt + 1) * XW_KT);
            const float4* p1 = (const float4*)(xrow1 + (kt + 1) * XW_KT);
            ld0 = v0 ? p0[kq] : zero4;
            ld1 = v1 ? p1[kq] : zero4;
        }
        __syncthreads();
        const float* xr = &xb[r];
#pragma unroll
        for (int k = 0; k < XW_KT; k++) {
            float xv = xr[k * XW_S];
            float4 w4 = W4[(kt * XW_KT + k) * 4 + cg];
            acc.x += xv * w4.x;
            acc.y += xv * w4.y;
            acc.z += xv * w4.z;
            acc.w += xv * w4.w;
        }
    }
    int node = rowBase + r;
    if (node < N_NODES) {
        float dv = dinv[node];
        float4 o;
        o.x = dv * acc.x; o.y = dv * acc.y; o.z = dv * acc.z; o.w = dv * acc.w;
        ((float4*)h0s)[(size_t)node * 4 + cg] = o;
    }
}

// ---------------- aggregate 1, bucket-centric: one block per 128-node bucket ----------------
// 16-lane group per edge: one 64B line gather + fire-and-forget LDS float atomic.
__global__ void k_agg1(const float* __restrict__ h0s, const int* __restrict__ bstart,
                       const unsigned int* __restrict__ binned, const float* __restrict__ dinv,
                       const float* __restrict__ b1, float* __restrict__ h1) {
    __shared__ float acc[BWIDTH][HID + 1];   // pad 17: scramble banks for atomics
    int tid = threadIdx.x;
    int b = blockIdx.x;
    int base = b << SHIFT;
    for (int f = tid; f < BWIDTH * HID; f += 256) {
        int r = f >> 4, c = f & 15;
        int node = base + r;
        acc[r][c] = (node < N_NODES) ? h0s[(size_t)node * HID + c] : 0.f;  // self loop
    }
    __syncthreads();
    int e0 = bstart[b], e1 = bstart[b + 1];
    int g = tid >> 4, c = tid & 15;
    for (int e = e0 + g; e < e1; e += 16) {
        unsigned int w = binned[e];
        int s  = (int)(w & 0x1FFFFu);
        int dl = (int)(w >> 17);
        atomicAdd(&acc[dl][c], h0s[(size_t)s * HID + c]);
    }
    __syncthreads();
    for (int f = tid; f < BWIDTH * HID; f += 256) {
        int r = f >> 4, cc = f & 15;
        int node = base + r;
        if (node < N_NODES) {
            float o = dinv[node] * acc[r][cc] + b1[cc];
            h1[(size_t)node * HID + cc] = fmaxf(o, 0.f);
        }
    }
}

// ---------------- 10 fused hops + zs = dinv * (h @ W2) ----------------
__global__ void k_hops(const float* __restrict__ h1, const float* __restrict__ Wl,
                       const float* __restrict__ bl, const float* __restrict__ W2,
                       const float* __restrict__ dinv, float* __restrict__ zs) {
    int node = blockIdx.x * blockDim.x + threadIdx.x;
    if (node >= N_NODES) return;
    float h[HID];
    const float4* h4 = (const float4*)(h1 + (size_t)node * HID);
#pragma unroll
    for (int q = 0; q < HID / 4; q++) {
        float4 v = h4[q];
        h[q * 4 + 0] = v.x; h[q * 4 + 1] = v.y;
        h[q * 4 + 2] = v.z; h[q * 4 + 3] = v.w;
    }
    for (int it = 0; it < K_HOPS; it++) {
        float tm[HID];
#pragma unroll
        for (int c = 0; c < HID; c++) tm[c] = bl[c];
#pragma unroll
        for (int k = 0; k < HID; k++) {
            float hk = h[k];
#pragma unroll
            for (int c = 0; c < HID; c++) tm[c] += hk * Wl[k * HID + c];
        }
#pragma unroll
        for (int c = 0; c < HID; c++)
            h[c] = ALPHA * fmaxf(tm[c], 0.f) + (1.f - ALPHA) * h[c];
    }
    float dv = dinv[node];
    float zz[8];
#pragma unroll
    for (int c = 0; c < 8; c++) zz[c] = 0.f;
#pragma unroll
    for (int k = 0; k < HID; k++) {
        float hk = h[k];
#pragma unroll
        for (int c = 0; c < NCLS; c++) zz[c] += hk * W2[k * NCLS + c];
    }
    float4* z4 = (float4*)(zs + (size_t)node * 8);
    float4 v0, v1;
    v0.x = dv * zz[0]; v0.y = dv * zz[1]; v0.z = dv * zz[2]; v0.w = dv * zz[3];
    v1.x = dv * zz[4]; v1.y = dv * zz[5]; v1.z = dv * zz[6]; v1.w = 0.f;
    z4[0] = v0; z4[1] = v1;
}

// ---------------- aggregate 2 + log_softmax, bucket-centric ----------------
__global__ void k_agg2(const float* __restrict__ zs, const int* __restrict__ bstart,
                       const unsigned int* __restrict__ binned, const float* __restrict__ dinv,
                       const float* __restrict__ b2, float* __restrict__ out) {
    __shared__ float acc[BWIDTH][9];   // pad 9
    int tid = threadIdx.x;
    int b = blockIdx.x;
    int base = b << SHIFT;
    for (int f = tid; f < BWIDTH * 8; f += 256) {
        int r = f >> 3, c = f & 7;
        int node = base + r;
        acc[r][c] = (node < N_NODES) ? zs[(size_t)node * 8 + c] : 0.f;   // self loop
    }
    __syncthreads();
    int e0 = bstart[b], e1 = bstart[b + 1];
    int g = tid >> 3, c = tid & 7;
    for (int e = e0 + g; e < e1; e += 32) {
        unsigned int w = binned[e];
        int s  = (int)(w & 0x1FFFFu);
        int dl = (int)(w >> 17);
        atomicAdd(&acc[dl][c], zs[(size_t)s * 8 + c]);
    }
    __syncthreads();
#pragma unroll
    for (int p = 0; p < 4; p++) {
        int idx = p * 256 + tid;         // 0..1023
        int r = idx >> 3, cc = idx & 7;
        int node = base + r;
        float o = ((node < N_NODES) ? dinv[node] * acc[r][cc] : 0.f)
                  + ((cc < NCLS) ? b2[cc] : 0.f);
        float val = (cc < NCLS) ? o : -INFINITY;
        float m = val;
        m = fmaxf(m, __shfl_xor(m, 1));
        m = fmaxf(m, __shfl_xor(m, 2));
        m = fmaxf(m, __shfl_xor(m, 4));
        float ex = (cc < NCLS) ? expf(o - m) : 0.f;
        float ss = ex;
        ss += __shfl_xor(ss, 1);
        ss += __shfl_xor(ss, 2);
        ss += __shfl_xor(ss, 4);
        if (node < N_NODES && cc < NCLS)
            out[(size_t)node * NCLS + cc] = o - m - logf(ss);
    }
}

extern "C" void kernel_launch(void* const* d_in, const int* in_sizes, int n_in,
                              void* d_out, int out_size, void* d_ws, size_t ws_size,
                              hipStream_t stream) {
    const float* x  = (const float*)d_in[0];
    const int*   ei = (const int*)d_in[1];
    const float* W1 = (const float*)d_in[2];
    const float* b1 = (const float*)d_in[3];
    const float* Wl = (const float*)d_in[4];
    const float* bl = (const float*)d_in[5];
    const float* W2 = (const float*)d_in[6];
    const float* b2 = (const float*)d_in[7];
    float* out = (float*)d_out;

    int*   wsI = (int*)d_ws;
    float* wsF = (float*)d_ws;
    int*          bcnt   = wsI + OFF_BCNT;
    int*          bstart = wsI + OFF_BSTART;
    int*          bcur   = wsI + OFF_BCUR;
    float*        dinv   = wsF + OFF_DINV;
    unsigned int* binned = (unsigned int*)(wsI + OFF_BINNED);
    float*        h0s    = wsF + OFF_H0;
    float*        h1     = wsF + OFF_H1;
    float*        zs     = wsF + OFF_Z;

    const int* src = ei;
    const int* dst = ei + N_EDGES;

    hipMemsetAsync(bcnt, 0, NBUCK * sizeof(int), stream);

    k_bhist<<<1024, 256, 0, stream>>>(dst, bcnt);
    k_bscan<<<1, 1024, 0, stream>>>(bcnt, bstart, bcur);
    k_bin<<<A3_BLOCKS, 256, 0, stream>>>(src, dst, bcur, binned);
    k_deg<<<NBUCK, 256, 0, stream>>>(binned, bstart, dinv);
    k_xw1<<<(N_NODES + XW_ROWS - 1) / XW_ROWS, 256, 0, stream>>>(x, W1, dinv, h0s);
    k_agg1<<<NBUCK, 256, 0, stream>>>(h0s, bstart, binned, dinv, b1, h1);
    k_hops<<<(N_NODES + 255) / 256, 256, 0, stream>>>(h1, Wl, bl, W2, dinv, zs);
    k_agg2<<<NBUCK, 256, 0, stream>>>(zs, bstart, binned, dinv, b2, out);
}

// Round 6
// 601.627 us; speedup vs baseline: 1.6126x; 1.6126x over previous
//
#include <hip/hip_runtime.h>
#include <math.h>

#define N_NODES 100000
#define N_EDGES 3200000
#define F_IN    512
#define HID     16
#define NCLS    7
#define ALPHA   0.1f
#define K_HOPS  10

// bucketing: 128 nodes per bucket
#define SHIFT   7
#define BWIDTH  128
#define NBUCK   ((N_NODES + BWIDTH - 1) / BWIDTH)   // 782
#define CHUNK   8192
#define EPT     (CHUNK / 256)                        // 32 edges per thread
#define A3_BLOCKS ((N_EDGES + CHUNK - 1) / CHUNK)   // 391

// ---- workspace layout (4-byte element offsets); ws ~819 MB, no aliasing ----
#define OFF_BCNT    0u          // int[782]
#define OFF_BSTART  1024u       // int[783]
#define OFF_BCUR    2048u       // int[782]
#define OFF_RP      3072u       // int[100001]
#define OFF_DINV    103424u     // float[100000]
#define OFF_COL     203776u     // int[3200000]
#define OFF_BINNED  3403776u    // uint[3200000]
#define OFF_H0      6603776u    // float[100000*16]
#define OFF_H1      8203776u    // float[100000*16]
#define OFF_Z       9803776u    // float[100000*8]
// total = 10603776 elems = 42.4 MB

// ---------------- A1: global bucket histogram ----------------
__global__ void k_bhist(const int* __restrict__ dst, int* __restrict__ bcnt) {
    __shared__ int h[NBUCK];
    int tid = threadIdx.x;
    for (int i = tid; i < NBUCK; i += 256) h[i] = 0;
    __syncthreads();
    for (int e = blockIdx.x * 256 + tid; e < N_EDGES; e += gridDim.x * 256)
        atomicAdd(&h[dst[e] >> SHIFT], 1);
    __syncthreads();
    for (int i = tid; i < NBUCK; i += 256) {
        int v = h[i];
        if (v) atomicAdd(&bcnt[i], v);
    }
}

// ---------------- A2: scan bucket counts ----------------
__global__ void k_bscan(const int* __restrict__ bcnt, int* __restrict__ bstart,
                        int* __restrict__ bcur) {
    __shared__ int s[1024];
    int tid = threadIdx.x;
    int v = (tid < NBUCK) ? bcnt[tid] : 0;
    s[tid] = v;
    __syncthreads();
    for (int off = 1; off < 1024; off <<= 1) {
        int t = (tid >= off) ? s[tid - off] : 0;
        __syncthreads();
        s[tid] += t;
        __syncthreads();
    }
    if (tid < NBUCK) {
        int ex = s[tid] - v;     // exclusive
        bstart[tid] = ex;
        bcur[tid] = ex;
    }
    if (tid == 0) bstart[NBUCK] = N_EDGES;
}

// ---------------- A3: binned scatter of packed edges ----------------
// binned[pos] = (dst&127)<<17 | src   (src < 2^17); dst cached in regs across passes
__global__ void k_bin(const int* __restrict__ src, const int* __restrict__ dst,
                      int* __restrict__ bcur, unsigned int* __restrict__ binned) {
    __shared__ int ha[NBUCK];
    __shared__ int gbase[NBUCK];
    __shared__ int lcur[NBUCK];
    int tid = threadIdx.x;
    int e0 = blockIdx.x * CHUNK;
    int e1 = e0 + CHUNK;
    if (e1 > N_EDGES) e1 = N_EDGES;
    for (int i = tid; i < NBUCK; i += 256) ha[i] = 0;
    __syncthreads();
    int dloc[EPT];
#pragma unroll
    for (int i = 0; i < EPT; i++) {
        int e = e0 + tid + i * 256;
        dloc[i] = (e < e1) ? dst[e] : -1;
        if (dloc[i] >= 0) atomicAdd(&ha[dloc[i] >> SHIFT], 1);
    }
    __syncthreads();
    for (int s = tid; s < NBUCK; s += 256) {
        int c = ha[s];
        lcur[s] = 0;
        gbase[s] = c ? atomicAdd(&bcur[s], c) : 0;
    }
    __syncthreads();
#pragma unroll
    for (int i = 0; i < EPT; i++) {
        int d = dloc[i];
        if (d >= 0) {
            int e = e0 + tid + i * 256;
            int bk = d >> SHIFT;
            int idx = atomicAdd(&lcur[bk], 1);
            binned[gbase[bk] + idx] =
                ((unsigned int)(d & (BWIDTH - 1)) << 17) | (unsigned int)src[e];
        }
    }
}

// ---------------- B: per-bucket CSR (count, scan, rp/dinv, col scatter) ----------------
__global__ void k_csr(const unsigned int* __restrict__ binned, const int* __restrict__ bstart,
                      int* __restrict__ rp, float* __restrict__ dinv, int* __restrict__ col) {
    __shared__ int cnt[BWIDTH];
    __shared__ int s[BWIDTH];
    __shared__ int cur[BWIDTH];
    int tid = threadIdx.x;
    int b = blockIdx.x;
    int base = b << SHIFT;
    int e0 = bstart[b], e1 = bstart[b + 1];
    if (tid < BWIDTH) cnt[tid] = 0;
    __syncthreads();
    for (int e = e0 + tid; e < e1; e += 256)
        atomicAdd(&cnt[binned[e] >> 17], 1);
    __syncthreads();
    int v = 0;
    if (tid < BWIDTH) { v = cnt[tid]; s[tid] = v; }
    __syncthreads();
    for (int off = 1; off < BWIDTH; off <<= 1) {
        int t = 0;
        if (tid < BWIDTH && tid >= off) t = s[tid - off];
        __syncthreads();
        if (tid < BWIDTH) s[tid] += t;
        __syncthreads();
    }
    if (tid < BWIDTH) {
        int ex = s[tid] - v;
        cur[tid] = ex;
        int node = base + tid;
        if (node < N_NODES) {
            rp[node] = e0 + ex;
            dinv[node] = rsqrtf((float)(v + 1));
        }
    }
    if (b == 0 && tid == 0) rp[N_NODES] = N_EDGES;
    __syncthreads();
    for (int e = e0 + tid; e < e1; e += 256) {
        unsigned int w = binned[e];
        int ln = (int)(w >> 17);
        int p = atomicAdd(&cur[ln], 1);
        col[e0 + p] = (int)(w & 0x1FFFFu);
    }
}

// ---------------- h0s = dinv * (x @ W1): coalesced LDS-tiled GEMM ----------------
#define XW_ROWS 64
#define XW_KT   32
#define XW_S    65
#define XW_NT   (F_IN / XW_KT)   // 16 tiles
__global__ void k_xw1(const float* __restrict__ x, const float* __restrict__ W,
                      const float* __restrict__ dinv, float* __restrict__ h0s) {
    __shared__ float xT[2][XW_KT * XW_S];
    int tid = threadIdx.x;
    int rowBase = blockIdx.x * XW_ROWS;

    int rf0 = tid >> 3, kq = tid & 7;
    int rf1 = rf0 + 32;
    bool v0 = (rowBase + rf0) < N_NODES;
    bool v1 = (rowBase + rf1) < N_NODES;
    const float* xrow0 = x + (size_t)(rowBase + rf0) * F_IN;
    const float* xrow1 = x + (size_t)(rowBase + rf1) * F_IN;

    int r  = tid & 63;
    int cg = __builtin_amdgcn_readfirstlane(tid >> 6);   // wave-uniform -> s_load W
    const float4* W4 = (const float4*)W;

    float4 zero4 = make_float4(0.f, 0.f, 0.f, 0.f);
    float4 acc = zero4;
    float4 ld0 = v0 ? ((const float4*)xrow0)[kq] : zero4;
    float4 ld1 = v1 ? ((const float4*)xrow1)[kq] : zero4;

    for (int kt = 0; kt < XW_NT; kt++) {
        int buf = kt & 1;
        float* xb = xT[buf];
        int kb = kq * 4;
        xb[(kb + 0) * XW_S + rf0] = ld0.x;
        xb[(kb + 1) * XW_S + rf0] = ld0.y;
        xb[(kb + 2) * XW_S + rf0] = ld0.z;
        xb[(kb + 3) * XW_S + rf0] = ld0.w;
        xb[(kb + 0) * XW_S + rf1] = ld1.x;
        xb[(kb + 1) * XW_S + rf1] = ld1.y;
        xb[(kb + 2) * XW_S + rf1] = ld1.z;
        xb[(kb + 3) * XW_S + rf1] = ld1.w;
        if (kt + 1 < XW_NT) {
            const float4* p0 = (const float4*)(xrow0 + (kt + 1) * XW_KT);
            const float4* p1 = (const float4*)(xrow1 + (kt + 1) * XW_KT);
            ld0 = v0 ? p0[kq] : zero4;
            ld1 = v1 ? p1[kq] : zero4;
        }
        __syncthreads();
        const float* xr = &xb[r];
#pragma unroll
        for (int k = 0; k < XW_KT; k++) {
            float xv = xr[k * XW_S];
            float4 w4 = W4[(kt * XW_KT + k) * 4 + cg];
            acc.x += xv * w4.x;
            acc.y += xv * w4.y;
            acc.z += xv * w4.z;
            acc.w += xv * w4.w;
        }
    }
    int node = rowBase + r;
    if (node < N_NODES) {
        float dv = dinv[node];
        float4 o;
        o.x = dv * acc.x; o.y = dv * acc.y; o.z = dv * acc.z; o.w = dv * acc.w;
        ((float4*)h0s)[(size_t)node * 4 + cg] = o;
    }
}

// ---------------- aggregate 1: one wave per node ----------------
// lane = c + 16*eo; 4 edges in flight; butterfly-reduce over eo.
__global__ void k_agg1(const float* __restrict__ h0s, const int* __restrict__ rp,
                       const int* __restrict__ col, const float* __restrict__ dinv,
                       const float* __restrict__ b1, float* __restrict__ h1) {
    int node = (blockIdx.x * blockDim.x + threadIdx.x) >> 6;
    if (node >= N_NODES) return;
    int lane = threadIdx.x & 63;
    int c = lane & 15, eo = lane >> 4;
    int e0 = rp[node], e1 = rp[node + 1];
    float acc = 0.f;
    for (int e = e0 + eo; e < e1; e += 4)
        acc += h0s[(size_t)col[e] * HID + c];
    acc += __shfl_xor(acc, 16);
    acc += __shfl_xor(acc, 32);
    float o = dinv[node] * (acc + h0s[(size_t)node * HID + c]) + b1[c];
    if (eo == 0) h1[(size_t)node * HID + c] = fmaxf(o, 0.f);
}

// ---------------- 10 fused hops + zs = dinv * (h @ W2) ----------------
__global__ void k_hops(const float* __restrict__ h1, const float* __restrict__ Wl,
                       const float* __restrict__ bl, const float* __restrict__ W2,
                       const float* __restrict__ dinv, float* __restrict__ zs) {
    int node = blockIdx.x * blockDim.x + threadIdx.x;
    if (node >= N_NODES) return;
    float h[HID];
    const float4* h4 = (const float4*)(h1 + (size_t)node * HID);
#pragma unroll
    for (int q = 0; q < HID / 4; q++) {
        float4 v = h4[q];
        h[q * 4 + 0] = v.x; h[q * 4 + 1] = v.y;
        h[q * 4 + 2] = v.z; h[q * 4 + 3] = v.w;
    }
    for (int it = 0; it < K_HOPS; it++) {
        float tm[HID];
#pragma unroll
        for (int c = 0; c < HID; c++) tm[c] = bl[c];
#pragma unroll
        for (int k = 0; k < HID; k++) {
            float hk = h[k];
#pragma unroll
            for (int c = 0; c < HID; c++) tm[c] += hk * Wl[k * HID + c];
        }
#pragma unroll
        for (int c = 0; c < HID; c++)
            h[c] = ALPHA * fmaxf(tm[c], 0.f) + (1.f - ALPHA) * h[c];
    }
    float dv = dinv[node];
    float zz[8];
#pragma unroll
    for (int c = 0; c < 8; c++) zz[c] = 0.f;
#pragma unroll
    for (int k = 0; k < HID; k++) {
        float hk = h[k];
#pragma unroll
        for (int c = 0; c < NCLS; c++) zz[c] += hk * W2[k * NCLS + c];
    }
    float4* z4 = (float4*)(zs + (size_t)node * 8);
    float4 v0, v1;
    v0.x = dv * zz[0]; v0.y = dv * zz[1]; v0.z = dv * zz[2]; v0.w = dv * zz[3];
    v1.x = dv * zz[4]; v1.y = dv * zz[5]; v1.z = dv * zz[6]; v1.w = 0.f;
    z4[0] = v0; z4[1] = v1;
}

// ---------------- aggregate 2 + log_softmax: one wave per node ----------------
// lane = c + 8*eo; 8 edges in flight; butterfly over eo then softmax over c.
__global__ void k_agg2(const float* __restrict__ zs, const int* __restrict__ rp,
                       const int* __restrict__ col, const float* __restrict__ dinv,
                       const float* __restrict__ b2, float* __restrict__ out) {
    int node = (blockIdx.x * blockDim.x + threadIdx.x) >> 6;
    if (node >= N_NODES) return;
    int lane = threadIdx.x & 63;
    int c = lane & 7, eo = lane >> 3;
    int e0 = rp[node], e1 = rp[node + 1];
    float acc = 0.f;
    for (int e = e0 + eo; e < e1; e += 8)
        acc += zs[(size_t)col[e] * 8 + c];
    acc += __shfl_xor(acc, 8);
    acc += __shfl_xor(acc, 16);
    acc += __shfl_xor(acc, 32);
    float o = dinv[node] * (acc + zs[(size_t)node * 8 + c]) + ((c < NCLS) ? b2[c] : 0.f);
    float val = (c < NCLS) ? o : -INFINITY;
    float m = val;
    m = fmaxf(m, __shfl_xor(m, 1));
    m = fmaxf(m, __shfl_xor(m, 2));
    m = fmaxf(m, __shfl_xor(m, 4));
    float ex = (c < NCLS) ? expf(o - m) : 0.f;
    float ss = ex;
    ss += __shfl_xor(ss, 1);
    ss += __shfl_xor(ss, 2);
    ss += __shfl_xor(ss, 4);
    if (eo == 0 && c < NCLS) out[(size_t)node * NCLS + c] = o - m - logf(ss);
}

extern "C" void kernel_launch(void* const* d_in, const int* in_sizes, int n_in,
                              void* d_out, int out_size, void* d_ws, size_t ws_size,
                              hipStream_t stream) {
    const float* x  = (const float*)d_in[0];
    const int*   ei = (const int*)d_in[1];
    const float* W1 = (const float*)d_in[2];
    const float* b1 = (const float*)d_in[3];
    const float* Wl = (const float*)d_in[4];
    const float* bl = (const float*)d_in[5];
    const float* W2 = (const float*)d_in[6];
    const float* b2 = (const float*)d_in[7];
    float* out = (float*)d_out;

    int*   wsI = (int*)d_ws;
    float* wsF = (float*)d_ws;
    int*          bcnt   = wsI + OFF_BCNT;
    int*          bstart = wsI + OFF_BSTART;
    int*          bcur   = wsI + OFF_BCUR;
    int*          rp     = wsI + OFF_RP;
    float*        dinv   = wsF + OFF_DINV;
    int*          col    = wsI + OFF_COL;
    unsigned int* binned = (unsigned int*)(wsI + OFF_BINNED);
    float*        h0s    = wsF + OFF_H0;
    float*        h1     = wsF + OFF_H1;
    float*        zs     = wsF + OFF_Z;

    const int* src = ei;
    const int* dst = ei + N_EDGES;

    hipMemsetAsync(bcnt, 0, NBUCK * sizeof(int), stream);

    k_bhist<<<1024, 256, 0, stream>>>(dst, bcnt);
    k_bscan<<<1, 1024, 0, stream>>>(bcnt, bstart, bcur);
    k_bin<<<A3_BLOCKS, 256, 0, stream>>>(src, dst, bcur, binned);
    k_csr<<<NBUCK, 256, 0, stream>>>(binned, bstart, rp, dinv, col);
    k_xw1<<<(N_NODES + XW_ROWS - 1) / XW_ROWS, 256, 0, stream>>>(x, W1, dinv, h0s);
    k_agg1<<<(N_NODES * 64 + 255) / 256, 256, 0, stream>>>(h0s, rp, col, dinv, b1, h1);
    k_hops<<<(N_NODES + 255) / 256, 256, 0, stream>>>(h1, Wl, bl, W2, dinv, zs);
    k_agg2<<<(N_NODES * 64 + 255) / 256, 256, 0, stream>>>(zs, rp, col, dinv, b2, out);
}